// Round 9
// baseline (44488.947 us; speedup 1.0000x reference)
//
#include <hip/hip_runtime.h>

// Persistent 4-layer LSTM, MFMA split-bf16, XCD-LOCAL recurrence sync.
// H=256, B=32, SEQ=1024, L=4.
//
// Architecture (round 9 = round 8 with a SOUND local-flag mechanism):
//   * The same-layer h-exchange is the only cycle in the dep graph -> it sets
//     the pipeline period. Each layer is pinned to one XCD (claimed by REAL
//     XCC_ID + IC rank atomic); its h-exchange runs through that XCD's L2.
//   * R8 HANG ROOT CAUSE: global_atomic_add is DEVICE-scope (executes at IC,
//     per guide m20) -> flag updates landed in IC while the sc0 poll re-read
//     a clean stale L2 line forever. FIX: flags are single-writer plain
//     STORES of the epoch value into the same L2 the data uses (store-hit
//     updates the cached line); poll = monolithic load+waitcnt asm (sc0).
//   * Hedges so ANY wrong assumption terminates instead of hanging:
//       - every local flag also mirrored to IC via proven sc0sc1 path;
//         local poll switches to the mirror after 256 tries.
//       - rendezvous / xfeed polls have large iteration caps that break
//         (finite wrong results + counters instead of a 600s timeout).
//   * Cross-layer x-feed (acyclic, absorbed into pipeline offset) goes
//     through IC exactly as in R8: double-store h (local + sc0sc1 feed copy
//     into x_data slab l+1), feed flag published one step late (after the
//     next step's __syncthreads vmcnt(0) drained the sc1 stores).
//   * Placement is deadlock-proof: 512 WGs x 256thr, launch_bounds(256,2)
//     -> all co-resident (2/CU) -> each XCD holds 64 candidates; ranks 0..31
//     on XCDs 0..3 work, everyone else exits. Correctness never depends on
//     the (undefined) dispatch->XCD mapping.

#define HID  256
#define BAT  32
#define SEQL 1024
#define NLAY 4
#define NE   (HID*BAT)       // 8192
#define WGPL 32              // WGs per layer
#define GSTR 36              // lds gate-exchange row stride (floats)

// workspace layout (ints)
#define WS_CNT 0                           // [8]  per-XCD rank counters (IC)
#define WS_RDY 8                           // [1]  rendezvous counter (IC)
#define WS_LF  16                          // local flags, stride 16 ints (64B)
#define WS_MF  (WS_LF + NLAY*WGPL*16)      // IC mirror flags, stride 1
#define WS_XF  (WS_MF + NLAY*WGPL)         // x-feed flags (IC), stride 1
#define WS_TOT (WS_XF + NLAY*WGPL)         // 2320 ints ~ 9.3 KB

typedef __attribute__((ext_vector_type(8))) short bf16x8;
typedef __attribute__((ext_vector_type(4))) float f32x4;

union U8 { bf16x8 v; unsigned short s[8]; unsigned u[4]; };

__device__ __forceinline__ unsigned short bf16_rne(float f) {
    unsigned u = __float_as_uint(f);
    u += 0x7FFFu + ((u >> 16) & 1u);
    return (unsigned short)(u >> 16);
}
__device__ __forceinline__ float bf16_to_f(unsigned short h) {
    return __uint_as_float(((unsigned)h) << 16);
}
__device__ __forceinline__ unsigned pack_hl(float f) {
    unsigned short hi = bf16_rne(f);
    unsigned short lo = bf16_rne(f - bf16_to_f(hi));
    return (((unsigned)hi) << 16) | lo;
}

// IC-coherent load/store (device scope)
__device__ __forceinline__ uint4 ld_cohx4(const unsigned* p) {
    uint4 r;
    asm volatile("global_load_dwordx4 %0, %1, off sc0 sc1" : "=v"(r) : "v"(p) : "memory");
    return r;
}
__device__ __forceinline__ void st_coh(unsigned* p, unsigned v) {
    asm volatile("global_store_dword %0, %1, off sc0 sc1" :: "v"(p), "v"(v) : "memory");
}
// XCD-local (L2) load: bypass L1 only
__device__ __forceinline__ uint4 ld_locx4(const unsigned* p) {
    uint4 r;
    asm volatile("global_load_dwordx4 %0, %1, off sc0" : "=v"(r) : "v"(p) : "memory");
    return r;
}
// plain load/store (lands in the issuing XCD's L2; L1 is write-through)
__device__ __forceinline__ uint4 ld_plainx4(const unsigned* p) {
    uint4 r;
    asm volatile("global_load_dwordx4 %0, %1, off" : "=v"(r) : "v"(p) : "memory");
    return r;
}
__device__ __forceinline__ void st_plain(unsigned* p, unsigned v) {
    asm volatile("global_store_dword %0, %1, off" :: "v"(p), "v"(v) : "memory");
}
// local flag poll: load + waitcnt in ONE asm block; the consumer compare is
// data-dependent on the output -> cannot be hoisted above the drain.
__device__ __forceinline__ int ld_flag_l2(const int* p) {
    int r;
    asm volatile("global_load_dword %0, %1, off sc0\n\ts_waitcnt vmcnt(0)"
                 : "=v"(r) : "v"(p) : "memory");
    return r;
}
__device__ __forceinline__ void waitcnt0() {
    asm volatile("s_waitcnt vmcnt(0)" ::: "memory");
}

__device__ __forceinline__ float sigm(float x)  { return 1.0f / (1.0f + __expf(-x)); }
__device__ __forceinline__ float tanhx(float x) { return 1.0f - 2.0f / (__expf(2.0f * x) + 1.0f); }

// In-place pack of layer-0 input x: fp32 -> (bf16hi<<16)|bf16lo, elementwise.
__global__ __launch_bounds__(256) void pack_x(unsigned* xp) {
    int i = (blockIdx.x * 256 + threadIdx.x) * 4;   // SEQ*NE = 8192*1024 covered exactly
    float4 f = *(const float4*)((const float*)xp + i);
    uint4 u;
    u.x = pack_hl(f.x); u.y = pack_hl(f.y);
    u.z = pack_hl(f.z); u.w = pack_hl(f.w);
    *(uint4*)(xp + i) = u;
}

__global__ __launch_bounds__(256, 2)
void lstm_mfma(unsigned* __restrict__ hslab,       // h_data (slot 0 = fp32 h0; s>=1 = local hbuf)
               const float* __restrict__ c_data,
               const float* __restrict__ W,
               const float* __restrict__ R,
               const float* __restrict__ bias,
               unsigned* __restrict__ xdata,        // x_data: slab0 packed in; slabs 1..4 = feeds
               float* __restrict__ out,
               int* __restrict__ ws)
{
    __shared__ float ldsg[32 * GSTR];
    __shared__ int role;

    const int tid = threadIdx.x;

    // ---- XCD identity + rank claim (layer = actual XCD) ----
    int xcc;
    asm volatile("s_getreg_b32 %0, hwreg(HW_REG_XCC_ID)" : "=s"(xcc));
    if (tid == 0)
        role = __hip_atomic_fetch_add(&ws[WS_CNT + (xcc & 7)], 1,
                                      __ATOMIC_RELAXED, __HIP_MEMORY_SCOPE_AGENT);
    __syncthreads();
    const int l = xcc & 7;
    const int w = role;
    if (l >= NLAY || w >= WGPL) return;   // XCDs 4..7 and surplus ranks exit

    // ---- reset own LOCAL flag (L2 path), rendezvous on IC counter ----
    int* lfp_own = ws + WS_LF + (l * WGPL + w) * 16;
    int* mfp_own = ws + WS_MF + l * WGPL + w;
    if (tid == 0) {
        st_plain((unsigned*)lfp_own, 0u);
        waitcnt0();
        __hip_atomic_fetch_add(&ws[WS_RDY], 1,
                               __ATOMIC_RELAXED, __HIP_MEMORY_SCOPE_AGENT);
        int rtr = 0;
        while (__hip_atomic_load(&ws[WS_RDY], __ATOMIC_RELAXED,
                                 __HIP_MEMORY_SCOPE_AGENT) < NLAY * WGPL) {
            if (++rtr > (1 << 22)) break;    // terminate-not-hang hedge
            __builtin_amdgcn_s_sleep(1);
        }
    }
    __syncthreads();

    const int wv   = tid >> 6;
    const int lane = tid & 63;
    const int mh   = wv & 1;          // batch half
    const int nh   = wv >> 1;         // row half
    const int ln15 = lane & 15;
    const int kq   = lane >> 4;       // 0..3 k-block

    const int n_loc = nh * 16 + ln15;             // local gate-row 0..31
    const int gate  = n_loc >> 3;
    const int uu    = n_loc & 7;
    const int grow  = gate * HID + w * 8 + uu;    // global gate-row in [0,1024)
    const int bg    = mh * 16 + ln15;             // batch for A-frags

    // ---- resident weight fragments: Bhi/Blo[s], s=0..15 (K=512) ----
    bf16x8 Bhi[16], Blo[16];
    {
        const float* Wl = W + (size_t)l * 4 * HID * HID;
        const float* Rl = R + (size_t)l * 4 * HID * HID;
        #pragma unroll
        for (int s = 0; s < 16; ++s) {
            int k0 = s * 32 + kq * 8;
            const float* src = (k0 < HID) ? (Wl + (size_t)grow * HID + k0)
                                          : (Rl + (size_t)grow * HID + (k0 - HID));
            float4 f0 = *(const float4*)src;
            float4 f1 = *(const float4*)(src + 4);
            float ff[8] = {f0.x, f0.y, f0.z, f0.w, f1.x, f1.y, f1.z, f1.w};
            U8 hi, lo;
            #pragma unroll
            for (int j = 0; j < 8; ++j) {
                hi.s[j] = bf16_rne(ff[j]);
                lo.s[j] = bf16_rne(ff[j] - bf16_to_f(hi.s[j]));
            }
            Bhi[s] = hi.v; Blo[s] = lo.v;
        }
    }

    const float bias_n = bias[l * 4 * HID + grow];

    // c-state owner: thread (uu2, b2)
    const int uu2 = tid >> 5;
    const int b2  = tid & 31;
    float cst = c_data[(size_t)l * (SEQL + 1) * NE + b2 * HID + w * 8 + uu2];

    unsigned* hbuf = hslab;  // slot (l,s) at ((l*(SEQL+1))+s)*NE
    const float* h0f = (const float*)hslab + (size_t)l * (SEQL + 1) * NE;

    for (int t = 0; t < SEQL; ++t) {
        // ---- dependency wait ----
        // wave0: LOCAL h flags via shared-L2 plain-store/sc0-load (fast);
        //        falls back to the proven IC mirror after 256 tries.
        // wave1: below-layer x-feed flags via proven IC path.
        if (wv == 0 && t > 0) {
            const int* lf = ws + WS_LF + (l * WGPL + (lane & 31)) * 16;
            const int* mf = ws + WS_MF + l * WGPL + (lane & 31);
            int tries = 0;
            for (;;) {
                int v = ld_flag_l2(lf);
                if (tries > 256) {
                    int vm = __hip_atomic_load(mf, __ATOMIC_RELAXED,
                                               __HIP_MEMORY_SCOPE_AGENT);
                    if (vm > v) v = vm;
                    if (tries > (1 << 22)) break;   // terminate-not-hang hedge
                }
                if (__all(v >= t)) break;
                ++tries;
            }
        }
        if (wv == 1 && l > 0) {
            const int* xf = ws + WS_XF + (l - 1) * WGPL + (lane & 31);
            int tries = 0;
            for (;;) {
                int v = __hip_atomic_load(xf, __ATOMIC_RELAXED,
                                          __HIP_MEMORY_SCOPE_AGENT);
                if (__all(v >= t + 1)) break;
                if (++tries > (1 << 22)) break;     // terminate-not-hang hedge
                __builtin_amdgcn_s_sleep(1);
            }
        }
        __syncthreads();

        const unsigned* xsrc = xdata + ((size_t)l * SEQL + t) * NE;   // slab l
        const unsigned* hsrc = hbuf + ((size_t)l * (SEQL + 1) + t) * NE;
        uint4 araw[32];

        // ---- issue loads: h (local L2) first, then x; consume h-half first ----
        if (t > 0) {
            #pragma unroll
            for (int s = 8; s < 16; ++s) {
                const unsigned* p = hsrc + bg * HID + (s - 8) * 32 + kq * 8;
                araw[2 * s]     = ld_locx4(p);
                araw[2 * s + 1] = ld_locx4(p + 4);
            }
            if (l > 0) {
                #pragma unroll
                for (int s = 0; s < 8; ++s) {
                    const unsigned* p = xsrc + bg * HID + s * 32 + kq * 8;
                    araw[2 * s]     = ld_cohx4(p);     // IC (cross-XCD feed)
                    araw[2 * s + 1] = ld_cohx4(p + 4);
                }
            } else {
                #pragma unroll
                for (int s = 0; s < 8; ++s) {
                    const unsigned* p = xsrc + bg * HID + s * 32 + kq * 8;
                    araw[2 * s]     = ld_plainx4(p);   // static slab 0
                    araw[2 * s + 1] = ld_plainx4(p + 4);
                }
            }
        } else {
            // t==0: h0 is fp32 in h_data slot 0 (static) -> pack in regs
            #pragma unroll
            for (int s = 8; s < 16; ++s) {
                const float* hp = h0f + bg * HID + (s - 8) * 32 + kq * 8;
                float4 f0 = *(const float4*)hp;
                float4 f1 = *(const float4*)(hp + 4);
                uint4 a0, a1;
                a0.x = pack_hl(f0.x); a0.y = pack_hl(f0.y);
                a0.z = pack_hl(f0.z); a0.w = pack_hl(f0.w);
                a1.x = pack_hl(f1.x); a1.y = pack_hl(f1.y);
                a1.z = pack_hl(f1.z); a1.w = pack_hl(f1.w);
                araw[2 * s] = a0; araw[2 * s + 1] = a1;
            }
            if (l > 0) {
                #pragma unroll
                for (int s = 0; s < 8; ++s) {
                    const unsigned* p = xsrc + bg * HID + s * 32 + kq * 8;
                    araw[2 * s]     = ld_cohx4(p);
                    araw[2 * s + 1] = ld_cohx4(p + 4);
                }
            } else {
                #pragma unroll
                for (int s = 0; s < 8; ++s) {
                    const unsigned* p = xsrc + bg * HID + s * 32 + kq * 8;
                    araw[2 * s]     = ld_plainx4(p);
                    araw[2 * s + 1] = ld_plainx4(p + 4);
                }
            }
        }

        // ---- MFMA K-loop: h-half (s=8..15) first, then x-half ----
        f32x4 acc0 = {bias_n, bias_n, bias_n, bias_n};
        f32x4 acc1 = {0.f, 0.f, 0.f, 0.f};
        f32x4 acc2 = {0.f, 0.f, 0.f, 0.f};
        #pragma unroll
        for (int s2 = 0; s2 < 16; ++s2) {
            const int s = (s2 < 8) ? (s2 + 8) : (s2 - 8);
            if (s2 == 0 && t > 0)
                asm volatile("s_waitcnt vmcnt(16)" ::: "memory");  // h ready
            if (s2 == 8) waitcnt0();                               // x ready
            uint4 d0 = araw[2 * s], d1 = araw[2 * s + 1];
            U8 ahi, alo;
            ahi.u[0] = __builtin_amdgcn_perm(d0.y, d0.x, 0x07060302u);
            ahi.u[1] = __builtin_amdgcn_perm(d0.w, d0.z, 0x07060302u);
            ahi.u[2] = __builtin_amdgcn_perm(d1.y, d1.x, 0x07060302u);
            ahi.u[3] = __builtin_amdgcn_perm(d1.w, d1.z, 0x07060302u);
            alo.u[0] = __builtin_amdgcn_perm(d0.y, d0.x, 0x05040100u);
            alo.u[1] = __builtin_amdgcn_perm(d0.w, d0.z, 0x05040100u);
            alo.u[2] = __builtin_amdgcn_perm(d1.y, d1.x, 0x05040100u);
            alo.u[3] = __builtin_amdgcn_perm(d1.w, d1.z, 0x05040100u);
            acc0 = __builtin_amdgcn_mfma_f32_16x16x32_bf16(ahi.v, Bhi[s], acc0, 0, 0, 0);
            acc1 = __builtin_amdgcn_mfma_f32_16x16x32_bf16(ahi.v, Blo[s], acc1, 0, 0, 0);
            acc2 = __builtin_amdgcn_mfma_f32_16x16x32_bf16(alo.v, Bhi[s], acc2, 0, 0, 0);
        }
        f32x4 cc = acc0 + acc1;
        cc = cc + acc2;

        // ---- exchange gates via LDS ----
        *(f32x4*)&ldsg[n_loc * GSTR + mh * 16 + kq * 4] = cc;
        __syncthreads();   // implicit vmcnt(0) per thread: last step's sc1
                           // feed stores are fully drained for ALL threads here

        // publish x-feed flag for step t-1 (its sc1 stores now drained)
        if (l < NLAY - 1 && t > 0 && tid == 0)
            __hip_atomic_fetch_add(&ws[WS_XF + l * WGPL + w], 1,
                                   __ATOMIC_RELAXED, __HIP_MEMORY_SCOPE_AGENT);

        // ---- elementwise update by cell owner (uu2, b2) ----
        float hv;
        unsigned dw;
        {
            float gi = ldsg[(0 * 8 + uu2) * GSTR + b2];
            float gf = ldsg[(1 * 8 + uu2) * GSTR + b2];
            float gg = ldsg[(2 * 8 + uu2) * GSTR + b2];
            float go = ldsg[(3 * 8 + uu2) * GSTR + b2];
            float iv = sigm(gi), fv = sigm(gf), gv = tanhx(gg), ov = sigm(go);
            cst = fv * cst + iv * gv;
            hv = ov * tanhx(cst);
            dw = pack_hl(hv);
        }
        unsigned* hdst = hbuf + ((size_t)l * (SEQL + 1) + (t + 1)) * NE
                       + b2 * HID + w * 8 + uu2;
        st_plain(hdst, dw);                       // local copy (this XCD's L2)
        if (l < NLAY - 1) {
            unsigned* xdst = xdata + ((size_t)(l + 1) * SEQL + t) * NE
                           + b2 * HID + w * 8 + uu2;
            st_coh(xdst, dw);                     // IC feed copy (fire)
            asm volatile("s_waitcnt vmcnt(1)" ::: "memory");  // local h done
        } else {
            waitcnt0();                           // local h (+prior out) done
        }
        asm volatile("s_barrier" ::: "memory");   // raw: do NOT drain the feed
        if (tid == 0) {
            // epoch publish: plain store to the SHARED L2 (store-hit updates
            // the pollers' cached line) + IC mirror via the proven path.
            st_plain((unsigned*)lfp_own, (unsigned)(t + 1));
            st_coh((unsigned*)mfp_own, (unsigned)(t + 1));
        }
        if (l == NLAY - 1)
            out[(size_t)t * NE + b2 * HID + w * 8 + uu2] = hv;  // fire, off path
    }

    // tail: publish the final x-feed flag (feed SEQL-1)
    if (l < NLAY - 1) {
        waitcnt0();
        __syncthreads();
        if (tid == 0)
            __hip_atomic_fetch_add(&ws[WS_XF + l * WGPL + w], 1,
                                   __ATOMIC_RELAXED, __HIP_MEMORY_SCOPE_AGENT);
    }
}

extern "C" void kernel_launch(void* const* d_in, const int* in_sizes, int n_in,
                              void* d_out, int out_size, void* d_ws, size_t ws_size,
                              hipStream_t stream) {
    unsigned*    h_data = (unsigned*)d_in[0];
    unsigned*    x_data = (unsigned*)d_in[1];
    float*       c_data = (float*)d_in[2];
    const float* W      = (const float*)d_in[3];
    const float* R      = (const float*)d_in[4];
    const float* bias   = (const float*)d_in[5];
    float* out = (float*)d_out;

    const size_t flag_bytes = (size_t)WS_TOT * sizeof(int);
    int* ws;
    if (ws_size >= flag_bytes) ws = (int*)d_ws;
    else                       ws = (int*)(c_data + NE);  // c_data slot [0][1]: unused
    hipMemsetAsync(ws, 0, flag_bytes, stream);

    // pack layer-0 x in place (SEQ*NE elements = 8192 blocks * 256 thr * 4)
    pack_x<<<dim3(8192), dim3(256), 0, stream>>>(x_data);

    // 512 WGs: with launch_bounds(256,2) all are co-resident (2 WGs/CU) ->
    // every XCD holds exactly 64 candidates -> rank claim is deadlock-free;
    // 128 participate (32 per XCD on XCDs 0..3), the rest exit.
    lstm_mfma<<<dim3(512), dim3(256), 0, stream>>>(
        h_data, c_data, W, R, bias, x_data, out, ws);
}